// Round 3
// baseline (62.023 us; speedup 1.0000x reference)
//
#include <hip/hip_runtime.h>
#include <math.h>

#define BB 64
#define TT 2000
#define DD 512
#define HH 256
#define KK 5
#define PP (3*KK)             // 15
#define TCHUNKS 80
#define TCHUNK (TT/TCHUNKS)   // 25
#define D4 (DD/4)             // 128

typedef __attribute__((ext_vector_type(4))) float floatv4;

// ws layout (floats):
//   [0, BB*16)                       params: [b][0..4]=m_k, [b][8..12]=inv_s_k
//   [1024, 1024 + BB*TCHUNKS*DD)     partials (64*80*512 = 2.62M floats, 10.5MB)

// ---------------------------------------------------------------------------
// Kernel 1: per-batch MLP (state@W1 -> tanh -> @W2 -> exp) -> m_k, 1/s_k.
// softmax over the singleton axis == 1, so mixture weights drop out.
// ---------------------------------------------------------------------------
__global__ __launch_bounds__(256) void mlp_params_kernel(
    const float* __restrict__ state,   // (B,1,D)
    const float* __restrict__ W1,      // (D,H) row-major
    const float* __restrict__ b1,      // (H)
    const float* __restrict__ W2,      // (H,3K) row-major
    const float* __restrict__ b2,      // (3K)
    float* __restrict__ ws_params)     // (B,16)
{
    const int b    = blockIdx.x;
    const int tid  = threadIdx.x;
    const int wave = tid >> 6;          // 0..3
    const int lane = tid & 63;

    __shared__ float s_state[DD];
    __shared__ float s_part[4][HH];
    __shared__ float hs[HH];
    __shared__ float s_red[16][17];
    __shared__ float pr[PP];

    for (int d = tid; d < DD; d += 256) s_state[d] = state[(size_t)b * DD + d];
    __syncthreads();

    // h: wave w covers d in [128w,128w+128); lane owns outputs 4*lane..4*lane+3
    {
        const int d0 = wave * 128;
        const float4* w1v = (const float4*)W1;
        float4 acc = make_float4(0.f, 0.f, 0.f, 0.f);
        #pragma unroll 16
        for (int dd = 0; dd < 128; ++dd) {
            const int d = d0 + dd;
            const float s  = s_state[d];
            const float4 w = w1v[(size_t)d * 64 + lane];
            acc.x += s * w.x; acc.y += s * w.y;
            acc.z += s * w.z; acc.w += s * w.w;
        }
        s_part[wave][4*lane+0] = acc.x;
        s_part[wave][4*lane+1] = acc.y;
        s_part[wave][4*lane+2] = acc.z;
        s_part[wave][4*lane+3] = acc.w;
    }
    __syncthreads();

    hs[tid] = tanhf(b1[tid] + s_part[0][tid] + s_part[1][tid]
                            + s_part[2][tid] + s_part[3][tid]);
    __syncthreads();

    // params: 16 groups of 16 threads; group p computes param p (p<15)
    {
        const int p = tid >> 4;
        const int g = tid & 15;
        float a = 0.f;
        if (p < PP) {
            #pragma unroll
            for (int i = 0; i < 16; ++i)
                a += hs[g + 16*i] * W2[(size_t)(g + 16*i) * PP + p];
        }
        s_red[p][g] = a;
    }
    __syncthreads();
    if (tid < PP) {
        float a = b2[tid];
        #pragma unroll
        for (int g = 0; g < 16; ++g) a += s_red[tid][g];
        pr[tid] = expf(a);
    }
    __syncthreads();

    if (tid < KK) {
        ws_params[(size_t)b * 16 + tid]     = pr[3*tid];            // mean
        ws_params[(size_t)b * 16 + 8 + tid] = 1.0f / pr[3*tid + 1]; // 1/scale
    }
}

// ---------------------------------------------------------------------------
// Kernel 2: recompute align for chunk, then
// partial[b,c,d] = sum_{t in chunk c} align[b,t] * enc_z[b,t,d]
// 5120 blocks — streaming, HBM-bound. Nontemporal enc_z loads (zero reuse).
// ---------------------------------------------------------------------------
__global__ __launch_bounds__(128) void reduce_partial_kernel(
    const float* __restrict__ enc_z,    // (B,T,D)
    const float* __restrict__ ws_params,// (B,16)
    float* __restrict__ partial)        // (B,TCHUNKS,D)
{
    const int b   = blockIdx.x;
    const int c   = blockIdx.y;
    const int tid = threadIdx.x;       // 0..127 -> float4 column

    __shared__ float al[TCHUNK];
    __shared__ float pr[16];
    if (tid < 16) pr[tid] = ws_params[(size_t)b * 16 + tid];
    __syncthreads();

    if (tid < TCHUNK) {
        const float tf = (float)(c * TCHUNK + tid);
        float a = 0.0f;
        #pragma unroll
        for (int k = 0; k < KK; ++k) {
            const float m  = pr[k];
            const float is = pr[8 + k];
            const float hi = (tf + 0.5f - m) * is;
            const float lo = (tf - 0.5f - m) * is;
            a += 1.0f / (1.0f + expf(-hi)) - 1.0f / (1.0f + expf(-lo));
        }
        al[tid] = a;
    }
    __syncthreads();

    const floatv4* e4 = (const floatv4*)enc_z
                      + (size_t)(b * TT + c * TCHUNK) * D4 + tid;

    float ax = 0.f, ay = 0.f, az = 0.f, aw = 0.f;
    #pragma unroll
    for (int t = 0; t < TCHUNK; ++t) {
        const float a   = al[t];
        const floatv4 v = __builtin_nontemporal_load(&e4[(size_t)t * D4]);
        ax += a * v.x; ay += a * v.y; az += a * v.z; aw += a * v.w;
    }
    floatv4 acc; acc.x = ax; acc.y = ay; acc.z = az; acc.w = aw;
    ((floatv4*)partial)[(size_t)(b * TCHUNKS + c) * D4 + tid] = acc;
}

// ---------------------------------------------------------------------------
// Kernel 3: context[b,d] = sum_c partial[b,c,d]
// ---------------------------------------------------------------------------
__global__ __launch_bounds__(128) void final_reduce_kernel(
    const float* __restrict__ partial, // (B,TCHUNKS,D)
    float* __restrict__ out)           // (B,1,D)
{
    const int b   = blockIdx.x;
    const int tid = threadIdx.x;       // 0..127

    const float4* p4 = (const float4*)partial + (size_t)b * TCHUNKS * D4 + tid;
    float4 acc = make_float4(0.f, 0.f, 0.f, 0.f);
    #pragma unroll 16
    for (int c = 0; c < TCHUNKS; ++c) {
        const float4 v = p4[(size_t)c * D4];
        acc.x += v.x; acc.y += v.y; acc.z += v.z; acc.w += v.w;
    }
    ((float4*)out)[(size_t)b * D4 + tid] = acc;
}

extern "C" void kernel_launch(void* const* d_in, const int* in_sizes, int n_in,
                              void* d_out, int out_size, void* d_ws, size_t ws_size,
                              hipStream_t stream) {
    const float* state = (const float*)d_in[0];
    const float* enc_z = (const float*)d_in[1];
    const float* W1    = (const float*)d_in[2];
    const float* b1    = (const float*)d_in[3];
    const float* W2    = (const float*)d_in[4];
    const float* b2    = (const float*)d_in[5];
    float* out = (float*)d_out;

    float* ws_params  = (float*)d_ws;                   // B*16 floats
    float* ws_partial = ws_params + (size_t)BB * 16;    // B*TCHUNKS*D floats

    mlp_params_kernel<<<BB, 256, 0, stream>>>(state, W1, b1, W2, b2, ws_params);
    reduce_partial_kernel<<<dim3(BB, TCHUNKS), 128, 0, stream>>>(enc_z, ws_params, ws_partial);
    final_reduce_kernel<<<BB, 128, 0, stream>>>(ws_partial, out);
}

// Round 4
// 17.042 us; speedup vs baseline: 3.6395x; 3.6395x over previous
//
#include <hip/hip_runtime.h>
#include <math.h>

#define BB 64
#define TT 2000
#define DD 512
#define HH 256
#define KK 5
#define PP (3*KK)             // 15
#define TCHUNKS 40
#define TCHUNK (TT/TCHUNKS)   // 50
#define D4 (DD/4)             // 128

// ws layout (floats):
//   [0, BB*16)                       params: [b][0..4]=m_k, [b][8..12]=inv_s_k,
//                                            [b][15]=t_cut
//   [1024, 1024 + BB*TCHUNKS*DD)     partials (only chunks with t0 < t_cut written)

// ---------------------------------------------------------------------------
// Kernel 1: per-batch MLP (state@W1 -> tanh -> @W2 -> exp) -> m_k, 1/s_k, t_cut.
// softmax over the singleton axis == 1, so mixture weights drop out.
// align[b,t] = sum_k sigmoid((t+.5-m)/s)-sigmoid((t-.5-m)/s): logistic tails
// decay e^{-(t-m)/s}; beyond t_cut = max_k(m + 36 s + 1) total mass < 1e-12.
// ---------------------------------------------------------------------------
__global__ __launch_bounds__(1024) void mlp_params_kernel(
    const float* __restrict__ state,   // (B,1,D)
    const float* __restrict__ W1,      // (D,H) row-major
    const float* __restrict__ b1,      // (H)
    const float* __restrict__ W2,      // (H,3K) row-major
    const float* __restrict__ b2,      // (3K)
    float* __restrict__ ws_params)     // (B,16)
{
    const int b     = blockIdx.x;
    const int tid   = threadIdx.x;
    const int q     = tid & 63;        // output quad: cols 4q..4q+3
    const int slice = tid >> 6;        // 0..15 -> d in [32*slice, 32*slice+32)

    __shared__ float s_state[DD];
    __shared__ float s_part[16][HH];   // [slice][col]
    __shared__ float hs[HH];
    __shared__ float s_red[16][17];
    __shared__ float pr[PP];

    if (tid < DD) s_state[tid] = state[(size_t)b * DD + tid];
    __syncthreads();

    // h-pre: 16-way split over d; wave w (=slice) reads w1v[d*64+lane] coalesced
    {
        const float4* w1v = (const float4*)W1;
        const int d0 = slice * 32;
        float4 acc = make_float4(0.f, 0.f, 0.f, 0.f);
        #pragma unroll 16
        for (int dd = 0; dd < 32; ++dd) {
            const int d    = d0 + dd;
            const float s  = s_state[d];
            const float4 w = w1v[(size_t)d * 64 + q];
            acc.x += s * w.x; acc.y += s * w.y;
            acc.z += s * w.z; acc.w += s * w.w;
        }
        s_part[slice][4*q+0] = acc.x;
        s_part[slice][4*q+1] = acc.y;
        s_part[slice][4*q+2] = acc.z;
        s_part[slice][4*q+3] = acc.w;
    }
    __syncthreads();

    if (tid < HH) {
        float a = b1[tid];
        #pragma unroll
        for (int s = 0; s < 16; ++s) a += s_part[s][tid];
        hs[tid] = tanhf(a);
    }
    __syncthreads();

    // params: 16 groups of 16 threads; group p computes param p (p<15)
    if (tid < 256) {
        const int p = tid >> 4;
        const int g = tid & 15;
        float a = 0.f;
        if (p < PP) {
            #pragma unroll
            for (int i = 0; i < 16; ++i)
                a += hs[g + 16*i] * W2[(size_t)(g + 16*i) * PP + p];
        }
        s_red[p][g] = a;
    }
    __syncthreads();
    if (tid < PP) {
        float a = b2[tid];
        #pragma unroll
        for (int g = 0; g < 16; ++g) a += s_red[tid][g];
        pr[tid] = expf(a);
    }
    __syncthreads();

    if (tid == 0) {
        float tc = 1.0f;
        #pragma unroll
        for (int k = 0; k < KK; ++k)
            tc = fmaxf(tc, pr[3*k] + 36.0f * pr[3*k+1] + 1.0f);
        ws_params[(size_t)b * 16 + 15] = tc;
    }
    if (tid < KK) {
        ws_params[(size_t)b * 16 + tid]     = pr[3*tid];            // mean
        ws_params[(size_t)b * 16 + 8 + tid] = 1.0f / pr[3*tid + 1]; // 1/scale
    }
}

// ---------------------------------------------------------------------------
// Kernel 2: partial[b,c,d] = sum_{t in chunk c} align[b,t] * enc_z[b,t,d]
// Blocks whose chunk lies entirely beyond t_cut exit without touching enc_z.
// ---------------------------------------------------------------------------
__global__ __launch_bounds__(128) void reduce_partial_kernel(
    const float* __restrict__ enc_z,    // (B,T,D)
    const float* __restrict__ ws_params,// (B,16)
    float* __restrict__ partial)        // (B,TCHUNKS,D)
{
    const int b   = blockIdx.x;
    const int c   = blockIdx.y;
    const int tid = threadIdx.x;       // 0..127 -> float4 column

    __shared__ float al[TCHUNK];
    __shared__ float pr[16];
    if (tid < 16) pr[tid] = ws_params[(size_t)b * 16 + tid];
    __syncthreads();

    const int t0 = c * TCHUNK;
    if ((float)t0 >= pr[15]) return;   // block-uniform: whole chunk is zero

    if (tid < TCHUNK) {
        const float tf = (float)(t0 + tid);
        float a = 0.0f;
        #pragma unroll
        for (int k = 0; k < KK; ++k) {
            const float m  = pr[k];
            const float is = pr[8 + k];
            const float hi = (tf + 0.5f - m) * is;
            const float lo = (tf - 0.5f - m) * is;
            a += 1.0f / (1.0f + expf(-hi)) - 1.0f / (1.0f + expf(-lo));
        }
        al[tid] = a;
    }
    __syncthreads();

    const float4* e4 = (const float4*)enc_z + (size_t)(b * TT + t0) * D4 + tid;

    float ax = 0.f, ay = 0.f, az = 0.f, aw = 0.f;
    #pragma unroll 10
    for (int t = 0; t < TCHUNK; ++t) {
        const float a  = al[t];
        const float4 v = e4[(size_t)t * D4];
        ax += a * v.x; ay += a * v.y; az += a * v.z; aw += a * v.w;
    }
    float4 acc = make_float4(ax, ay, az, aw);
    ((float4*)partial)[(size_t)(b * TCHUNKS + c) * D4 + tid] = acc;
}

// ---------------------------------------------------------------------------
// Kernel 3: context[b,d] = sum over active chunks of partial[b,c,d]
// Active predicate matches kernel 2 exactly: c*TCHUNK < t_cut.
// ---------------------------------------------------------------------------
__global__ __launch_bounds__(128) void final_reduce_kernel(
    const float* __restrict__ partial,  // (B,TCHUNKS,D)
    const float* __restrict__ ws_params,// (B,16)
    float* __restrict__ out)            // (B,1,D)
{
    const int b   = blockIdx.x;
    const int tid = threadIdx.x;       // 0..127

    const float tcut = ws_params[(size_t)b * 16 + 15];
    int nc = 0;
    while (nc < TCHUNKS && (float)(nc * TCHUNK) < tcut) ++nc;

    const float4* p4 = (const float4*)partial + (size_t)b * TCHUNKS * D4 + tid;
    float4 acc = make_float4(0.f, 0.f, 0.f, 0.f);
    for (int c = 0; c < nc; ++c) {
        const float4 v = p4[(size_t)c * D4];
        acc.x += v.x; acc.y += v.y; acc.z += v.z; acc.w += v.w;
    }
    ((float4*)out)[(size_t)b * D4 + tid] = acc;
}

extern "C" void kernel_launch(void* const* d_in, const int* in_sizes, int n_in,
                              void* d_out, int out_size, void* d_ws, size_t ws_size,
                              hipStream_t stream) {
    const float* state = (const float*)d_in[0];
    const float* enc_z = (const float*)d_in[1];
    const float* W1    = (const float*)d_in[2];
    const float* b1    = (const float*)d_in[3];
    const float* W2    = (const float*)d_in[4];
    const float* b2    = (const float*)d_in[5];
    float* out = (float*)d_out;

    float* ws_params  = (float*)d_ws;                   // B*16 floats
    float* ws_partial = ws_params + (size_t)BB * 16;    // B*TCHUNKS*D floats

    mlp_params_kernel<<<BB, 1024, 0, stream>>>(state, W1, b1, W2, b2, ws_params);
    reduce_partial_kernel<<<dim3(BB, TCHUNKS), 128, 0, stream>>>(enc_z, ws_params, ws_partial);
    final_reduce_kernel<<<BB, 128, 0, stream>>>(ws_partial, ws_params, out);
}